// Round 5
// baseline (16502.495 us; speedup 1.0000x reference)
//
#include <hip/hip_runtime.h>
#include <stdint.h>

#define TT    8192
#define EMBD  128
#define HID   256
#define G4    1024      // 4*HID
#define NTAGS 17
#define NBLK  16        // recurrence participants (goal: all on one XCD)
#define SH    16        // HID / NBLK
#define PKW   36        // padded u32 stride per k-quarter of packed-bf16 h
#define REG_GRID 256    // registration grid for lstm

typedef unsigned int u32;
typedef unsigned short u16;
typedef float fvec4 __attribute__((ext_vector_type(4)));

__device__ __forceinline__ float sigf(float x) { return 1.f / (1.f + __expf(-x)); }
__device__ __forceinline__ float tanhf_fast(float x) {
    x = fminf(15.f, fmaxf(-15.f, x));
    float a = __expf(2.f * x);
    return (a - 1.f) / (a + 1.f);
}

// sc0 = L1-bypass, serviced by the XCD-shared L2. Only useful for same-XCD
// communication — correctness never depends on it (mirror fallback).
__device__ __forceinline__ u32 load_u32_sc0(const u32* p) {
    u32 v;
    asm volatile("global_load_dword %0, %1, off sc0\n\ts_waitcnt vmcnt(0)"
                 : "=v"(v) : "v"(p) : "memory");
    return v;
}
__device__ __forceinline__ void store_u32_sc0(u32* p, u32 v) {
    asm volatile("global_store_dword %0, %1, off sc0" :: "v"(p), "v"(v) : "memory");
}

// Raw barrier: NO vmcnt drain (producer wave's L3 mirror store must stay in
// flight across it). LDS ordering via lgkmcnt.
__device__ __forceinline__ void block_sync() {
    asm volatile("s_waitcnt lgkmcnt(0)" ::: "memory");
    __builtin_amdgcn_s_barrier();
    asm volatile("" ::: "memory");
}

// ---------------------------------------------------------------------------
// Kernel A: xg[t][j] = dot(emb[tok[t]], W_ih[j]) + b_ih[j] + b_hh[j]
// Block 0 also inits the registration pool/winner and the mirror (tag 0).
// ---------------------------------------------------------------------------
__global__ __launch_bounds__(256) void xg_kernel(
    const int* __restrict__ tok, const float* __restrict__ emb,
    const float* __restrict__ Wih, const float* __restrict__ bih,
    const float* __restrict__ bhh, float* __restrict__ xg,
    int* __restrict__ pool, int* __restrict__ winner, u32* __restrict__ hx2)
{
    __shared__ __align__(16) float es[4][EMBD];
    const int tid = threadIdx.x;
    const int t0  = blockIdx.x * 4;

    if (blockIdx.x == 0) {
        if (tid < 16) pool[tid] = 0;
        if (tid == 16) *winner = -1;
        for (int i = tid; i < 2 * HID + 32; i += 256) hx2[i] = 0u;
    }

    for (int p = tid; p < 4 * EMBD; p += 256) {
        const int tt = p >> 7, k = p & 127;
        es[tt][k] = emb[(long)tok[t0 + tt] * EMBD + k];
    }
    __syncthreads();

#pragma unroll
    for (int q = 0; q < 4; ++q) {
        const int j = q * 256 + tid;
        const float4* wr = (const float4*)(Wih + (long)j * EMBD);
        float a0 = 0.f, a1 = 0.f, a2 = 0.f, a3 = 0.f;
#pragma unroll 8
        for (int k4 = 0; k4 < EMBD / 4; ++k4) {
            const float4 w  = wr[k4];
            const float4 e0 = ((const float4*)es[0])[k4];
            const float4 e1 = ((const float4*)es[1])[k4];
            const float4 e2 = ((const float4*)es[2])[k4];
            const float4 e3 = ((const float4*)es[3])[k4];
            a0 += w.x*e0.x + w.y*e0.y + w.z*e0.z + w.w*e0.w;
            a1 += w.x*e1.x + w.y*e1.y + w.z*e1.z + w.w*e1.w;
            a2 += w.x*e2.x + w.y*e2.y + w.z*e2.z + w.w*e2.w;
            a3 += w.x*e3.x + w.y*e3.y + w.z*e3.z + w.w*e3.w;
        }
        const float bb = bih[j] + bhh[j];
        xg[(long)(t0 + 0) * G4 + j] = a0 + bb;
        xg[(long)(t0 + 1) * G4 + j] = a1 + bb;
        xg[(long)(t0 + 2) * G4 + j] = a2 + bb;
        xg[(long)(t0 + 3) * G4 + j] = a3 + bb;
    }
}

// ---------------------------------------------------------------------------
// Kernel B: LSTM recurrence. 16 working blocks of 320 threads (5 waves).
//
// R9 result: producer-wave specialization PASSED but perf was flat vs R6 —
// the exchange micro-structure is NOT the bottleneck (store-poisoning theory
// disproven by experiment). The invariant term across all rounds is the
// matvec's LDS fan-out: 16x ds_read_b128 (256 B f32 h) per lane, 64 b128
// instr/CU/step ~= 770 cy of serialized DS-pipe occupancy (b128 ~12cy, m134).
//
// R10: h lives in LDS as PACKED bf16 pairs (numerically identical — h was
// already bf16-rounded for the exchange). Lane traffic halves: 8x b128 =
// 128 B/lane; unpack (shift/mask) runs on the VALU pipe, hidden under DS.
// Layout u32 hpk[2][4][PKW=36]: quarter q at word offset q*36 (144 B,
// 16B-aligned); per-instr bank spans 4q+4J are disjoint -> conflict-free.
// Writers use 16-bit LDS stores (consumer: its tid's h; leader: its gidx's).
// Secondary: activations applied in ALL lanes before the gate shuffles
// (act = g==2 ? tanh : sig, branch-free) — shortens the leader serial chain.
//
// Exchange unchanged from R9 (proven): wave 4 publishes UNCONDITIONALLY
// (sc0/L2 word + L3 mirror word every step; R1-grade liveness), raw
// s_barrier (no vmcnt drain), consumers use adaptive-kbud sc0 poll with
// mirror fallback.
// ---------------------------------------------------------------------------
__global__ __launch_bounds__(320, 1) void lstm_kernel(
    const float* __restrict__ Whh, const float* __restrict__ xg,
    u32* __restrict__ hx, u32* __restrict__ hx2,
    int* __restrict__ pool, int* __restrict__ winner)
{
    const int tid = threadIdx.x;

    u32 xcc;
    asm volatile("s_getreg_b32 %0, hwreg(HW_REG_XCC_ID, 0, 4)" : "=s"(xcc));
    xcc &= 15u;

    __shared__ int s_b;
    if (tid == 0) {
        int b = -1;
        const int slot = atomicAdd(&pool[xcc], 1);
        if (slot < NBLK) {
            if (slot == NBLK - 1) atomicCAS(winner, -1, (int)xcc);
            int w;
            while ((w = __hip_atomic_load(winner, __ATOMIC_RELAXED,
                                          __HIP_MEMORY_SCOPE_AGENT)) == -1)
                __builtin_amdgcn_s_sleep(8);
            if (w == (int)xcc) b = slot;
        }
        s_b = b;
    }
    __syncthreads();
    const int b = s_b;
    if (b < 0) return;                 // not part of the winning 16

    const bool prodw = (tid >= 256);   // wave 4 = publisher
    const int  w   = tid >> 6;
    const int  L   = tid & 63;
    const int  g   = L >> 4;
    const int  l15 = L & 15;
    const int  hi  = l15 >> 2;
    const int  q   = L & 3;
    // &1023: clamp wave-4's (unused) row into Whh bounds — w=4 would walk OOB.
    const int  row = (g * HID + b * SH + w * 4 + hi) & 1023;

    const fvec4* wsrc = (const fvec4*)(Whh + (long)row * HID + q * 64);
#define LOADW(J) fvec4 w##J = wsrc[J];
    LOADW(0)  LOADW(1)  LOADW(2)  LOADW(3)
    LOADW(4)  LOADW(5)  LOADW(6)  LOADW(7)
    LOADW(8)  LOADW(9)  LOADW(10) LOADW(11)
    LOADW(12) LOADW(13) LOADW(14) LOADW(15)
#undef LOADW
    asm volatile("" : "+v"(w0),  "+v"(w1),  "+v"(w2),  "+v"(w3),
                      "+v"(w4),  "+v"(w5),  "+v"(w6),  "+v"(w7),
                      "+v"(w8),  "+v"(w9),  "+v"(w10), "+v"(w11),
                      "+v"(w12), "+v"(w13), "+v"(w14), "+v"(w15));

    // packed-bf16 h: word (j>>6)*PKW + ((j&63)>>1), half j&1
    __shared__ __align__(16) u32 hpk[2][4 * PKW];
    for (int i = tid; i < 4 * PKW; i += 320) hpk[0][i] = 0u;   // h_0 = 0
    __syncthreads();

    float c_reg = 0.f;
    int   kbud  = 12;                  // adaptive sc0 spin budget
    const bool leader = (g == 0) && (q == 0);
    const int  gidx   = b * SH + w * 4 + hi;
    const bool remote = !prodw && ((tid >> 4) != b);

    // producer-wave indices (lane 0..63; only lanes 0..15 publish)
    const int  pl  = tid - 256;
    const int  pgw = b * SH + (pl & 15);

    const float* xgp = xg + row;
    float xg0 = 0.f, xg1 = 0.f;
    if (!prodw) { xg0 = xgp[0]; xg1 = xgp[G4]; }

#define UNLO(u) __uint_as_float((u) << 16)
#define UNHI(u) __uint_as_float((u) & 0xFFFF0000u)
#define ACC2(M, WA, WB) { const uint4 U = hq[M]; \
        p0 = __builtin_fmaf(WA.x, UNLO(U.x), p0); \
        p1 = __builtin_fmaf(WA.y, UNHI(U.x), p1); \
        p2 = __builtin_fmaf(WA.z, UNLO(U.y), p2); \
        p3 = __builtin_fmaf(WA.w, UNHI(U.y), p3); \
        p0 = __builtin_fmaf(WB.x, UNLO(U.z), p0); \
        p1 = __builtin_fmaf(WB.y, UNHI(U.z), p1); \
        p2 = __builtin_fmaf(WB.z, UNLO(U.w), p2); \
        p3 = __builtin_fmaf(WB.w, UNHI(U.w), p3); }

#define STEP(CUR, S_, XGV) { \
        if (!prodw) { \
            const uint4* hq = (const uint4*)&hpk[CUR][q * PKW]; \
            float p0 = 0.f, p1 = 0.f, p2 = 0.f, p3 = 0.f; \
            ACC2(0, w0,  w1)  ACC2(1, w2,  w3)  ACC2(2, w4,  w5) \
            ACC2(3, w6,  w7)  ACC2(4, w8,  w9)  ACC2(5, w10, w11) \
            ACC2(6, w12, w13) ACC2(7, w14, w15) \
            float p = (p0 + p1) + (p2 + p3); \
            p += __shfl_xor(p, 1, 64); \
            p += __shfl_xor(p, 2, 64); \
            const float pre = p + (XGV); \
            const float sg = sigf(pre); \
            const float th = tanhf_fast(pre); \
            const float act = (g == 2) ? th : sg; \
            const float vf = __shfl(act, 16 + l15, 64); \
            const float vg = __shfl(act, 32 + l15, 64); \
            const float vo = __shfl(act, 48 + l15, 64); \
            if (leader) { \
                c_reg = vf * c_reg + act * vg; \
                const float hn = vo * tanhf_fast(c_reg); \
                const u32 hb32 = __float_as_uint(hn); \
                const u32 rb   = (hb32 + 0x7FFFu + ((hb32 >> 16) & 1u)) >> 16; \
                ((u16*)&hpk[(CUR) ^ 1][(gidx >> 6) * PKW + ((gidx & 63) >> 1)]) \
                    [gidx & 1] = (u16)rb; \
            } \
        } \
        block_sync();  /* barrier-1: this block's fresh h staged in hpk[CUR^1] */ \
        if (prodw) { \
            asm volatile("s_waitcnt vmcnt(0)" ::: "memory"); /* prior stores retired */ \
            if (pl < 16) { \
                const u32 hv = (u32)((const u16*) \
                    &hpk[(CUR) ^ 1][(pgw >> 6) * PKW + ((pgw & 63) >> 1)])[pgw & 1]; \
                const u32 word = ((u32)((S_) + 1) << 16) | hv; \
                store_u32_sc0(&hx[(long)((S_) + 1) * HID + pgw], word); \
                __hip_atomic_store(&hx2[(((S_) + 1) & 1) * HID + pgw], word, \
                                   __ATOMIC_RELAXED, __HIP_MEMORY_SCOPE_AGENT); \
            } \
        } else if (remote) { \
            const u32 want = (u32)((S_) + 1) << 16; \
            u32* wp  = &hx[(long)((S_) + 1) * HID + tid]; \
            u32* wp2 = &hx2[(((S_) + 1) & 1) * HID + tid]; \
            u32 u; bool fast = false; \
            for (int it = 0; it < kbud; ++it) { \
                u = load_u32_sc0(wp); \
                if ((u & 0xFFFF0000u) == want) { fast = true; break; } \
            } \
            if (!fast) { \
                do { u = __hip_atomic_load(wp2, __ATOMIC_RELAXED, \
                                           __HIP_MEMORY_SCOPE_AGENT); } \
                while ((u & 0xFFFF0000u) != want); \
                kbud = 1; \
            } else { \
                kbud = 12; \
            } \
            ((u16*)&hpk[(CUR) ^ 1][(tid >> 6) * PKW + ((tid & 63) >> 1)]) \
                [tid & 1] = (u16)u; \
        } \
        block_sync();  /* barrier-2: hpk[CUR^1] complete; flip */ }

    for (int s = 0; s < TT; s += 2) {
        float xgn0 = 0.f, xgn1 = 0.f;
        if (!prodw) xgn0 = xgp[(long)(s + 2) * G4];   // covered by STEP(0) matvec
        STEP(0, s, xg0)
        if (!prodw) xgn1 = xgp[(long)(s + 3) * G4];
        STEP(1, s + 1, xg1)
        xg0 = xgn0; xg1 = xgn1;
    }
#undef STEP
#undef ACC2
#undef UNLO
#undef UNHI
}

// ---------------------------------------------------------------------------
// Kernel C: tag logits + log_softmax; unpacks bf16 h from tagged words.
// ---------------------------------------------------------------------------
__global__ __launch_bounds__(64) void out_kernel(
    const u32* __restrict__ hx, const float* __restrict__ Wout,
    const float* __restrict__ bout, float* __restrict__ out)
{
    const int t   = blockIdx.x;
    const int tid = threadIdx.x;
    __shared__ __align__(16) float hs[HID];
    __shared__ float lg[NTAGS];

    const uint4 uu = ((const uint4*)(hx + (long)(t + 1) * HID))[tid];
    hs[tid * 4 + 0] = __uint_as_float(uu.x << 16);
    hs[tid * 4 + 1] = __uint_as_float(uu.y << 16);
    hs[tid * 4 + 2] = __uint_as_float(uu.z << 16);
    hs[tid * 4 + 3] = __uint_as_float(uu.w << 16);
    __syncthreads();

    if (tid < NTAGS) {
        const float4* wr = (const float4*)(Wout + (long)tid * HID);
        float p = 0.f;
#pragma unroll 8
        for (int qq = 0; qq < HID / 4; ++qq) {
            const float4 w = wr[qq];
            const float4 h = ((const float4*)hs)[qq];
            p += w.x*h.x + w.y*h.y + w.z*h.z + w.w*h.w;
        }
        lg[tid] = p + bout[tid];
    }
    __syncthreads();

    if (tid < NTAGS) {
        float m = -1e30f;
        for (int gg = 0; gg < NTAGS; ++gg) m = fmaxf(m, lg[gg]);
        float ss = 0.f;
        for (int gg = 0; gg < NTAGS; ++gg) ss += __expf(lg[gg] - m);
        out[(long)t * NTAGS + tid] = lg[tid] - (m + __logf(ss));
    }
}

// ---------------------------------------------------------------------------
// ws layout (total 41,948,424 B):
//   xg     : 33,554,432 B
//   hx     :  8,389,632 B   (8193 * 256 tagged words)
//   hx2    :      2,176 B   (2 * 256 mirror + slack)
//   pool   :         64 B
//   winner :          4 B
// ---------------------------------------------------------------------------
extern "C" void kernel_launch(void* const* d_in, const int* in_sizes, int n_in,
                              void* d_out, int out_size, void* d_ws, size_t ws_size,
                              hipStream_t stream)
{
    const int*   tok  = (const int*)  d_in[0];
    const float* emb  = (const float*)d_in[1];
    const float* Wih  = (const float*)d_in[2];
    const float* Whh  = (const float*)d_in[3];
    const float* bih  = (const float*)d_in[4];
    const float* bhh  = (const float*)d_in[5];
    const float* Wout = (const float*)d_in[6];
    const float* bout = (const float*)d_in[7];
    float* out = (float*)d_out;

    char* ws = (char*)d_ws;
    float* xg     = (float*)(ws);
    u32*   hx     = (u32*)  (ws + 33554432UL);
    u32*   hx2    = (u32*)  (ws + 33554432UL + 8389632UL);
    int*   pool   = (int*)  (ws + 33554432UL + 8389632UL + 2176UL);
    int*   winner = (int*)  (ws + 33554432UL + 8389632UL + 2176UL + 64UL);

    xg_kernel  <<<TT / 4,   256, 0, stream>>>(tok, emb, Wih, bih, bhh, xg,
                                              pool, winner, hx2);
    lstm_kernel<<<REG_GRID, 320, 0, stream>>>(Whh, xg, hx, hx2, pool, winner);
    out_kernel <<<TT,       64,  0, stream>>>(hx, Wout, bout, out);
}

// Round 6
// 16354.126 us; speedup vs baseline: 1.0091x; 1.0091x over previous
//
#include <hip/hip_runtime.h>
#include <stdint.h>

#define TT    8192
#define EMBD  128
#define HID   256
#define G4    1024      // 4*HID
#define NTAGS 17
#define NBLK  16        // recurrence participants (goal: all on one XCD)
#define SH    16        // HID / NBLK
#define PKW   36        // padded u32 stride per k-quarter of packed-bf16 h
#define REG_GRID 256    // registration grid for lstm
#define DONE_IDX 540    // u32 index into hx2 slack: recurrence-done flag

typedef unsigned int u32;
typedef unsigned short u16;
typedef float fvec4 __attribute__((ext_vector_type(4)));

__device__ __forceinline__ float sigf(float x) { return 1.f / (1.f + __expf(-x)); }
__device__ __forceinline__ float tanhf_fast(float x) {
    x = fminf(15.f, fmaxf(-15.f, x));
    float a = __expf(2.f * x);
    return (a - 1.f) / (a + 1.f);
}

// sc0 = L1-bypass, serviced by the XCD-shared L2. Only useful for same-XCD
// communication — correctness never depends on it (mirror fallback).
__device__ __forceinline__ u32 load_u32_sc0(const u32* p) {
    u32 v;
    asm volatile("global_load_dword %0, %1, off sc0\n\ts_waitcnt vmcnt(0)"
                 : "=v"(v) : "v"(p) : "memory");
    return v;
}
__device__ __forceinline__ void store_u32_sc0(u32* p, u32 v) {
    asm volatile("global_store_dword %0, %1, off sc0" :: "v"(p), "v"(v) : "memory");
}

// Raw barrier: NO vmcnt drain (producer wave's L3 mirror store must stay in
// flight across it). LDS ordering via lgkmcnt.
__device__ __forceinline__ void block_sync() {
    asm volatile("s_waitcnt lgkmcnt(0)" ::: "memory");
    __builtin_amdgcn_s_barrier();
    asm volatile("" ::: "memory");
}

// ---------------------------------------------------------------------------
// Kernel A: xg[t][j] = dot(emb[tok[t]], W_ih[j]) + b_ih[j] + b_hh[j]
// Block 0 also inits the registration pool/winner, mirror, and done flag.
// ---------------------------------------------------------------------------
__global__ __launch_bounds__(256) void xg_kernel(
    const int* __restrict__ tok, const float* __restrict__ emb,
    const float* __restrict__ Wih, const float* __restrict__ bih,
    const float* __restrict__ bhh, float* __restrict__ xg,
    int* __restrict__ pool, int* __restrict__ winner, u32* __restrict__ hx2)
{
    __shared__ __align__(16) float es[4][EMBD];
    const int tid = threadIdx.x;
    const int t0  = blockIdx.x * 4;

    if (blockIdx.x == 0) {
        if (tid < 16) pool[tid] = 0;
        if (tid == 16) *winner = -1;
        for (int i = tid; i < 2 * HID + 32; i += 256) hx2[i] = 0u;  // incl. DONE_IDX
    }

    for (int p = tid; p < 4 * EMBD; p += 256) {
        const int tt = p >> 7, k = p & 127;
        es[tt][k] = emb[(long)tok[t0 + tt] * EMBD + k];
    }
    __syncthreads();

#pragma unroll
    for (int q = 0; q < 4; ++q) {
        const int j = q * 256 + tid;
        const float4* wr = (const float4*)(Wih + (long)j * EMBD);
        float a0 = 0.f, a1 = 0.f, a2 = 0.f, a3 = 0.f;
#pragma unroll 8
        for (int k4 = 0; k4 < EMBD / 4; ++k4) {
            const float4 w  = wr[k4];
            const float4 e0 = ((const float4*)es[0])[k4];
            const float4 e1 = ((const float4*)es[1])[k4];
            const float4 e2 = ((const float4*)es[2])[k4];
            const float4 e3 = ((const float4*)es[3])[k4];
            a0 += w.x*e0.x + w.y*e0.y + w.z*e0.z + w.w*e0.w;
            a1 += w.x*e1.x + w.y*e1.y + w.z*e1.z + w.w*e1.w;
            a2 += w.x*e2.x + w.y*e2.y + w.z*e2.z + w.w*e2.w;
            a3 += w.x*e3.x + w.y*e3.y + w.z*e3.z + w.w*e3.w;
        }
        const float bb = bih[j] + bhh[j];
        xg[(long)(t0 + 0) * G4 + j] = a0 + bb;
        xg[(long)(t0 + 1) * G4 + j] = a1 + bb;
        xg[(long)(t0 + 2) * G4 + j] = a2 + bb;
        xg[(long)(t0 + 3) * G4 + j] = a3 + bb;
    }
}

// ---------------------------------------------------------------------------
// Kernel B: LSTM recurrence. 16 working blocks of 320 threads (5 waves).
//
// R11 theory — DPM downclock. R6-R10 (weight residency, store-poisoning,
// producer-wave split, bf16-packed LDS) were ALL flat at ~19ms/2.32µs-step,
// while the @2.4GHz cycle budget says ~0.5µs/step. A ~4x constant multiplier
// that survives every structural edit = clock floor: 16/256 CUs busy,
// VALUBusy 1%, no MFMA, no HBM -> the governor never boosts; every latency
// is stretched uniformly, drowning all few-hundred-cycle improvements.
//
// Experiment (single variable vs R10): registration-LOSER blocks become
// BALLAST — dense register-only FP32 FMA spin (activity signal for DPM,
// zero memory traffic) until a done flag (hx2[DONE_IDX], set by block 0's
// producer wave after the last step) or a hard iteration cap (guaranteed
// termination; R7/R8 lesson: no unbounded loops). 256 blocks over 256 CUs
// -> winner CUs mostly keep 1 block; winner waves are latency-bound, so
// co-resident ballast fills idle issue slots rather than starving them.
//
// Recurrence structure (R9+R10, both verified): producer wave 4 publishes
// UNCONDITIONALLY (sc0/L2 + L3 mirror each step; R1-grade liveness); raw
// s_barrier (no vmcnt drain); consumers adaptive-kbud sc0 poll + mirror
// fallback; h packed bf16 in LDS (8x ds_read_b128 per lane).
// ---------------------------------------------------------------------------
__global__ __launch_bounds__(320, 1) void lstm_kernel(
    const float* __restrict__ Whh, const float* __restrict__ xg,
    u32* __restrict__ hx, u32* __restrict__ hx2,
    int* __restrict__ pool, int* __restrict__ winner)
{
    const int tid = threadIdx.x;

    u32 xcc;
    asm volatile("s_getreg_b32 %0, hwreg(HW_REG_XCC_ID, 0, 4)" : "=s"(xcc));
    xcc &= 15u;

    __shared__ int s_b;
    if (tid == 0) {
        int b = -1;
        const int slot = atomicAdd(&pool[xcc], 1);
        if (slot < NBLK) {
            if (slot == NBLK - 1) atomicCAS(winner, -1, (int)xcc);
            int w;
            while ((w = __hip_atomic_load(winner, __ATOMIC_RELAXED,
                                          __HIP_MEMORY_SCOPE_AGENT)) == -1)
                __builtin_amdgcn_s_sleep(8);
            if (w == (int)xcc) b = slot;
        }
        s_b = b;
    }
    __syncthreads();
    const int b = s_b;

    if (b < 0) {
        // ---- BALLAST: keep the clock governor fed while winners run ----
        float a0 = 1.0001f * (float)(tid + 1), a1 = a0 * 0.9993f;
        float a2 = a0 + 0.5f,                  a3 = a1 + 0.25f;
        const float m = 1.0000001f, d = 1e-7f;
        for (u32 i = 0; i < (1u << 21); ++i) {       // hard cap: guaranteed exit
#pragma unroll
            for (int r = 0; r < 4; ++r) {
                a0 = __builtin_fmaf(a0, m, d);
                a1 = __builtin_fmaf(a1, m, d);
                a2 = __builtin_fmaf(a2, m, d);
                a3 = __builtin_fmaf(a3, m, d);
            }
            if ((i & 255u) == 0u &&
                __hip_atomic_load(&hx2[DONE_IDX], __ATOMIC_RELAXED,
                                  __HIP_MEMORY_SCOPE_AGENT) != 0u)
                break;
        }
        asm volatile("" :: "v"(a0), "v"(a1), "v"(a2), "v"(a3));
        return;
    }

    const bool prodw = (tid >= 256);   // wave 4 = publisher
    const int  w   = tid >> 6;
    const int  L   = tid & 63;
    const int  g   = L >> 4;
    const int  l15 = L & 15;
    const int  hi  = l15 >> 2;
    const int  q   = L & 3;
    // &1023: clamp wave-4's (unused) row into Whh bounds — w=4 would walk OOB.
    const int  row = (g * HID + b * SH + w * 4 + hi) & 1023;

    const fvec4* wsrc = (const fvec4*)(Whh + (long)row * HID + q * 64);
#define LOADW(J) fvec4 w##J = wsrc[J];
    LOADW(0)  LOADW(1)  LOADW(2)  LOADW(3)
    LOADW(4)  LOADW(5)  LOADW(6)  LOADW(7)
    LOADW(8)  LOADW(9)  LOADW(10) LOADW(11)
    LOADW(12) LOADW(13) LOADW(14) LOADW(15)
#undef LOADW
    asm volatile("" : "+v"(w0),  "+v"(w1),  "+v"(w2),  "+v"(w3),
                      "+v"(w4),  "+v"(w5),  "+v"(w6),  "+v"(w7),
                      "+v"(w8),  "+v"(w9),  "+v"(w10), "+v"(w11),
                      "+v"(w12), "+v"(w13), "+v"(w14), "+v"(w15));

    // packed-bf16 h: word (j>>6)*PKW + ((j&63)>>1), half j&1
    __shared__ __align__(16) u32 hpk[2][4 * PKW];
    for (int i = tid; i < 4 * PKW; i += 320) hpk[0][i] = 0u;   // h_0 = 0
    __syncthreads();

    float c_reg = 0.f;
    int   kbud  = 12;                  // adaptive sc0 spin budget
    const bool leader = (g == 0) && (q == 0);
    const int  gidx   = b * SH + w * 4 + hi;
    const bool remote = !prodw && ((tid >> 4) != b);

    // producer-wave indices (lane 0..63; only lanes 0..15 publish)
    const int  pl  = tid - 256;
    const int  pgw = b * SH + (pl & 15);

    const float* xgp = xg + row;
    float xg0 = 0.f, xg1 = 0.f;
    if (!prodw) { xg0 = xgp[0]; xg1 = xgp[G4]; }

#define UNLO(u) __uint_as_float((u) << 16)
#define UNHI(u) __uint_as_float((u) & 0xFFFF0000u)
#define ACC2(M, WA, WB) { const uint4 U = hq[M]; \
        p0 = __builtin_fmaf(WA.x, UNLO(U.x), p0); \
        p1 = __builtin_fmaf(WA.y, UNHI(U.x), p1); \
        p2 = __builtin_fmaf(WA.z, UNLO(U.y), p2); \
        p3 = __builtin_fmaf(WA.w, UNHI(U.y), p3); \
        p0 = __builtin_fmaf(WB.x, UNLO(U.z), p0); \
        p1 = __builtin_fmaf(WB.y, UNHI(U.z), p1); \
        p2 = __builtin_fmaf(WB.z, UNLO(U.w), p2); \
        p3 = __builtin_fmaf(WB.w, UNHI(U.w), p3); }

#define STEP(CUR, S_, XGV) { \
        if (!prodw) { \
            const uint4* hq = (const uint4*)&hpk[CUR][q * PKW]; \
            float p0 = 0.f, p1 = 0.f, p2 = 0.f, p3 = 0.f; \
            ACC2(0, w0,  w1)  ACC2(1, w2,  w3)  ACC2(2, w4,  w5) \
            ACC2(3, w6,  w7)  ACC2(4, w8,  w9)  ACC2(5, w10, w11) \
            ACC2(6, w12, w13) ACC2(7, w14, w15) \
            float p = (p0 + p1) + (p2 + p3); \
            p += __shfl_xor(p, 1, 64); \
            p += __shfl_xor(p, 2, 64); \
            const float pre = p + (XGV); \
            const float sg = sigf(pre); \
            const float th = tanhf_fast(pre); \
            const float act = (g == 2) ? th : sg; \
            const float vf = __shfl(act, 16 + l15, 64); \
            const float vg = __shfl(act, 32 + l15, 64); \
            const float vo = __shfl(act, 48 + l15, 64); \
            if (leader) { \
                c_reg = vf * c_reg + act * vg; \
                const float hn = vo * tanhf_fast(c_reg); \
                const u32 hb32 = __float_as_uint(hn); \
                const u32 rb   = (hb32 + 0x7FFFu + ((hb32 >> 16) & 1u)) >> 16; \
                ((u16*)&hpk[(CUR) ^ 1][(gidx >> 6) * PKW + ((gidx & 63) >> 1)]) \
                    [gidx & 1] = (u16)rb; \
            } \
        } \
        block_sync();  /* barrier-1: this block's fresh h staged in hpk[CUR^1] */ \
        if (prodw) { \
            asm volatile("s_waitcnt vmcnt(0)" ::: "memory"); /* prior stores retired */ \
            if (pl < 16) { \
                const u32 hv = (u32)((const u16*) \
                    &hpk[(CUR) ^ 1][(pgw >> 6) * PKW + ((pgw & 63) >> 1)])[pgw & 1]; \
                const u32 word = ((u32)((S_) + 1) << 16) | hv; \
                store_u32_sc0(&hx[(long)((S_) + 1) * HID + pgw], word); \
                __hip_atomic_store(&hx2[(((S_) + 1) & 1) * HID + pgw], word, \
                                   __ATOMIC_RELAXED, __HIP_MEMORY_SCOPE_AGENT); \
            } \
        } else if (remote) { \
            const u32 want = (u32)((S_) + 1) << 16; \
            u32* wp  = &hx[(long)((S_) + 1) * HID + tid]; \
            u32* wp2 = &hx2[(((S_) + 1) & 1) * HID + tid]; \
            u32 u; bool fast = false; \
            for (int it = 0; it < kbud; ++it) { \
                u = load_u32_sc0(wp); \
                if ((u & 0xFFFF0000u) == want) { fast = true; break; } \
            } \
            if (!fast) { \
                do { u = __hip_atomic_load(wp2, __ATOMIC_RELAXED, \
                                           __HIP_MEMORY_SCOPE_AGENT); } \
                while ((u & 0xFFFF0000u) != want); \
                kbud = 1; \
            } else { \
                kbud = 12; \
            } \
            ((u16*)&hpk[(CUR) ^ 1][(tid >> 6) * PKW + ((tid & 63) >> 1)]) \
                [tid & 1] = (u16)u; \
        } \
        block_sync();  /* barrier-2: hpk[CUR^1] complete; flip */ }

    for (int s = 0; s < TT; s += 2) {
        float xgn0 = 0.f, xgn1 = 0.f;
        if (!prodw) xgn0 = xgp[(long)(s + 2) * G4];   // covered by STEP(0) matvec
        STEP(0, s, xg0)
        if (!prodw) xgn1 = xgp[(long)(s + 3) * G4];
        STEP(1, s + 1, xg1)
        xg0 = xgn0; xg1 = xgn1;
    }
#undef STEP
#undef ACC2
#undef UNLO
#undef UNHI

    // release the ballast
    if (b == 0 && prodw && pl == 0)
        __hip_atomic_store(&hx2[DONE_IDX], 1u, __ATOMIC_RELAXED,
                           __HIP_MEMORY_SCOPE_AGENT);
}

// ---------------------------------------------------------------------------
// Kernel C: tag logits + log_softmax; unpacks bf16 h from tagged words.
// ---------------------------------------------------------------------------
__global__ __launch_bounds__(64) void out_kernel(
    const u32* __restrict__ hx, const float* __restrict__ Wout,
    const float* __restrict__ bout, float* __restrict__ out)
{
    const int t   = blockIdx.x;
    const int tid = threadIdx.x;
    __shared__ __align__(16) float hs[HID];
    __shared__ float lg[NTAGS];

    const uint4 uu = ((const uint4*)(hx + (long)(t + 1) * HID))[tid];
    hs[tid * 4 + 0] = __uint_as_float(uu.x << 16);
    hs[tid * 4 + 1] = __uint_as_float(uu.y << 16);
    hs[tid * 4 + 2] = __uint_as_float(uu.z << 16);
    hs[tid * 4 + 3] = __uint_as_float(uu.w << 16);
    __syncthreads();

    if (tid < NTAGS) {
        const float4* wr = (const float4*)(Wout + (long)tid * HID);
        float p = 0.f;
#pragma unroll 8
        for (int qq = 0; qq < HID / 4; ++qq) {
            const float4 w = wr[qq];
            const float4 h = ((const float4*)hs)[qq];
            p += w.x*h.x + w.y*h.y + w.z*h.z + w.w*h.w;
        }
        lg[tid] = p + bout[tid];
    }
    __syncthreads();

    if (tid < NTAGS) {
        float m = -1e30f;
        for (int gg = 0; gg < NTAGS; ++gg) m = fmaxf(m, lg[gg]);
        float ss = 0.f;
        for (int gg = 0; gg < NTAGS; ++gg) ss += __expf(lg[gg] - m);
        out[(long)t * NTAGS + tid] = lg[tid] - (m + __logf(ss));
    }
}

// ---------------------------------------------------------------------------
// ws layout (total 41,948,424 B):
//   xg     : 33,554,432 B
//   hx     :  8,389,632 B   (8193 * 256 tagged words)
//   hx2    :      2,176 B   (2 * 256 mirror + slack; [540] = done flag)
//   pool   :         64 B
//   winner :          4 B
// ---------------------------------------------------------------------------
extern "C" void kernel_launch(void* const* d_in, const int* in_sizes, int n_in,
                              void* d_out, int out_size, void* d_ws, size_t ws_size,
                              hipStream_t stream)
{
    const int*   tok  = (const int*)  d_in[0];
    const float* emb  = (const float*)d_in[1];
    const float* Wih  = (const float*)d_in[2];
    const float* Whh  = (const float*)d_in[3];
    const float* bih  = (const float*)d_in[4];
    const float* bhh  = (const float*)d_in[5];
    const float* Wout = (const float*)d_in[6];
    const float* bout = (const float*)d_in[7];
    float* out = (float*)d_out;

    char* ws = (char*)d_ws;
    float* xg     = (float*)(ws);
    u32*   hx     = (u32*)  (ws + 33554432UL);
    u32*   hx2    = (u32*)  (ws + 33554432UL + 8389632UL);
    int*   pool   = (int*)  (ws + 33554432UL + 8389632UL + 2176UL);
    int*   winner = (int*)  (ws + 33554432UL + 8389632UL + 2176UL + 64UL);

    xg_kernel  <<<TT / 4,   256, 0, stream>>>(tok, emb, Wih, bih, bhh, xg,
                                              pool, winner, hx2);
    lstm_kernel<<<REG_GRID, 320, 0, stream>>>(Whh, xg, hx, hx2, pool, winner);
    out_kernel <<<TT,       64,  0, stream>>>(hx, Wout, bout, out);
}